// Round 9
// baseline (197.430 us; speedup 1.0000x reference)
//
#include <hip/hip_runtime.h>

#define F_DIM   128
#define C_DIM   100000
#define B_ROWS  512
#define ANGLE   0.5f
#define CPB     128            // classes per block
#define NCB     782            // ceil(100000/128); last tile has 96 OOB pad classes
#define OOB_PAD 96.0f          // pad classes contribute exp2(0)=1 each to row sums
#define LOG2E   1.4426950408889634f
#define GRID_MAIN 512          // 2 blocks/CU on 256 CUs; cb = bid, bid+512

typedef __attribute__((ext_vector_type(4))) float        f32x4;
typedef __attribute__((ext_vector_type(8))) short        bf16x8;
typedef __attribute__((ext_vector_type(4))) unsigned int u32x4;

// packed fp32->bf16 (RNE), 2 elements per instruction
static __device__ __forceinline__ unsigned int pk2(float a, float b) {
    unsigned int r;
    asm("v_cvt_pk_bf16_f32 %0, %1, %2" : "=v"(r) : "v"(a), "v"(b));
    return r;
}

// convert+swizzled-LDS-write of one staged w octet-column set (r7-verified)
static __device__ __forceinline__ void stage_write(unsigned short* lBt,
                                                   const f32x4* wr,
                                                   int cq, int ko)
{
    #pragma unroll
    for (int j = 0; j < 4; ++j) {
        const int cls = cq * 4 + j;
        union { u32x4 u; bf16x8 h; } c;
        c.u[0] = pk2(wr[0][j] * LOG2E, wr[1][j] * LOG2E);
        c.u[1] = pk2(wr[2][j] * LOG2E, wr[3][j] * LOG2E);
        c.u[2] = pk2(wr[4][j] * LOG2E, wr[5][j] * LOG2E);
        c.u[3] = pk2(wr[6][j] * LOG2E, wr[7][j] * LOG2E);
        const int f = (cls & 12) | ((cls ^ (cls >> 4)) & 3);
        *(bf16x8*)&lBt[cls * 128 + ((ko ^ f) << 3)] = c.h;
    }
}

// MFMA + exp2 over one staged 128-class tile; exp-sums atomically added into
// rowsum[512] (distinct addresses per block -> negligible contention).
static __device__ __forceinline__ void compute_cb(const unsigned short* lBt,
                                                  const float* __restrict__ feat,
                                                  float* __restrict__ rowsum,
                                                  int wv, int lane, int quad, int l15)
{
    #pragma unroll 1
    for (int half = 0; half < 2; ++half) {
        const int r0 = half << 8;

        // feat fragments: fB[s][ks] = f[b][k0..k0+7], b = r0+wv*32+s*16+l15
        bf16x8 fB[2][4];
        #pragma unroll
        for (int s = 0; s < 2; ++s) {
            const int b = r0 + wv * 32 + s * 16 + l15;
            #pragma unroll
            for (int ks = 0; ks < 4; ++ks) {
                const int k0 = ks * 32 + quad * 8;
                const f32x4 u0 = *(const f32x4*)(feat + b * F_DIM + k0);
                const f32x4 u1 = *(const f32x4*)(feat + b * F_DIM + k0 + 4);
                union { u32x4 u; bf16x8 h; } c;
                c.u[0] = pk2(u0[0], u0[1]); c.u[1] = pk2(u0[2], u0[3]);
                c.u[2] = pk2(u1[0], u1[1]); c.u[3] = pk2(u1[2], u1[3]);
                fB[s][ks] = c.h;
            }
        }

        float eA0 = 0.f, eA1 = 0.f, eA2 = 0.f, eA3 = 0.f;   // s=0 col
        float eB0 = 0.f, eB1 = 0.f, eB2 = 0.f, eB3 = 0.f;   // s=1 col
        #pragma unroll
        for (int m = 0; m < 8; ++m) {
            f32x4 a0 = {0.f, 0.f, 0.f, 0.f};
            f32x4 a1 = {0.f, 0.f, 0.f, 0.f};
            const int rb = (m * 16 + l15) * 128;
            const int fr = (l15 & 12) | ((l15 ^ m) & 3);   // f(row)
            #pragma unroll
            for (int ks = 0; ks < 4; ++ks) {
                const int pc = (ks * 4 + quad) ^ fr;
                const bf16x8 af = *(const bf16x8*)&lBt[rb + (pc << 3)];
                a0 = __builtin_amdgcn_mfma_f32_16x16x32_bf16(af, fB[0][ks], a0, 0, 0, 0);
                a1 = __builtin_amdgcn_mfma_f32_16x16x32_bf16(af, fB[1][ks], a1, 0, 0, 0);
            }
            eA0 += __builtin_amdgcn_exp2f(a0[0]); eA1 += __builtin_amdgcn_exp2f(a0[1]);
            eA2 += __builtin_amdgcn_exp2f(a0[2]); eA3 += __builtin_amdgcn_exp2f(a0[3]);
            eB0 += __builtin_amdgcn_exp2f(a1[0]); eB1 += __builtin_amdgcn_exp2f(a1[1]);
            eB2 += __builtin_amdgcn_exp2f(a1[2]); eB3 += __builtin_amdgcn_exp2f(a1[3]);
        }

        float esum0 = (eA0 + eA1) + (eA2 + eA3);
        float esum1 = (eB0 + eB1) + (eB2 + eB3);
        esum0 += __shfl_xor(esum0, 16); esum0 += __shfl_xor(esum0, 32);
        esum1 += __shfl_xor(esum1, 16); esum1 += __shfl_xor(esum1, 32);
        if (lane < 16) {
            const int r = r0 + wv * 32 + lane;
            atomicAdd(&rowsum[r],      esum0);
            atomicAdd(&rowsum[r + 16], esum1);
        }
    }
}

// wave-cooperative exact-fp32 target terms for rows whose target falls in
// this tile's class range (w columns L2-hot from staging). ~0.65 rows/block.
static __device__ __forceinline__ void do_targets(const float* __restrict__ feat,
                                                  const float* __restrict__ w,
                                                  float* __restrict__ margv,
                                                  float* __restrict__ expdot,
                                                  int c0, int tgt, int wv, int lane)
{
    unsigned long long mask = __ballot((unsigned)(tgt - c0) < CPB);
    while (mask) {
        const int src = (int)__ffsll(mask) - 1;
        mask &= mask - 1;
        const int row = wv * 64 + src;
        const int tb  = __shfl(tgt, src);
        const float f1 = feat[row * F_DIM + lane];
        const float f2 = feat[row * F_DIM + lane + 64];
        const float w1 = w[(size_t)lane * C_DIM + tb];
        const float w2 = w[(size_t)(lane + 64) * C_DIM + tb];
        float dot = fmaf(f1, w1, f2 * w2);
        float wsq = fmaf(w1, w1, w2 * w2);
        float fsq = fmaf(f1, f1, f2 * f2);
        #pragma unroll
        for (int off = 32; off > 0; off >>= 1) {
            dot += __shfl_xor(dot, off);
            wsq += __shfl_xor(wsq, off);
            fsq += __shfl_xor(fsq, off);
        }
        if (lane == src) {
            const float mod = sqrtf(fsq) * sqrtf(wsq);
            float ct = dot / (mod * 1.01f);
            ct = fminf(1.f, fmaxf(-1.f, ct));
            const float th = acosf(ct) + ANGLE;
            margv[row]  = mod * cosf(th);
            expdot[row] = expf(dot);
        }
    }
}

// ---------------------------------------------------------------------------
// arc_main: ONE compute dispatch. Persistent grid 512 x 512 threads
//   (2 blocks/CU), block bid handles class-tiles bid and bid+512.
//   Both tiles' staging loads are issued BEFORE the first barrier -> the two
//   HBM latency rounds merge into one. exp-sums go straight to rowsum[] via
//   atomicAdd (no pp array). Target-column terms computed wave-cooperatively
//   while the tile's w columns are L2-hot. The last block to finish
//   (device-scope counter, r3/r5/r8-validated fence pattern) computes the
//   512 per-row terms and the final reduction.
// ---------------------------------------------------------------------------
__global__ __launch_bounds__(512, 4)
void arc_main(const float* __restrict__ feat,
              const float* __restrict__ w,
              const int*   __restrict__ target,
              float* __restrict__ rowsum,    // [512], pre-zeroed
              float* __restrict__ margv,     // [512]
              float* __restrict__ expdot,    // [512]
              unsigned int* __restrict__ cnt,// [1], pre-zeroed
              float* __restrict__ out)
{
    __shared__ unsigned short lBt[128 * 128];   // [c][k] swizzled, 32 KB
    __shared__ unsigned int   sOld;

    const int tid  = threadIdx.x;
    const int bid  = blockIdx.x;
    const int lane = tid & 63;
    const int wv   = tid >> 6;
    const int quad = lane >> 4;
    const int l15  = lane & 15;
    const int tgt  = target[tid];

    const int  cb0  = bid;                 // always < NCB and pad-free
    const int  cb1  = bid + GRID_MAIN;
    const bool has2 = (cb1 < NCB);

    // ---- issue BOTH tiles' staging loads up front (one merged HBM round)
    const int cq = tid & 31;               // classes cq*4 .. cq*4+3
    const int ko = tid >> 5;               // k-octet 0..15
    f32x4 wr[8], wr2[8];
    {
        const float* wp = w + (size_t)ko * 8 * C_DIM + (cb0 * CPB + cq * 4);
        #pragma unroll
        for (int i = 0; i < 8; ++i)
            wr[i] = *(const f32x4*)(wp + (size_t)i * C_DIM);
    }
    if (has2) {
        const int gc = cb1 * CPB + cq * 4;
        if (gc < C_DIM) {                  // whole quad valid (C%4==0)
            const float* wp = w + (size_t)ko * 8 * C_DIM + gc;
            #pragma unroll
            for (int i = 0; i < 8; ++i)
                wr2[i] = *(const f32x4*)(wp + (size_t)i * C_DIM);
        } else {
            #pragma unroll
            for (int i = 0; i < 8; ++i)
                wr2[i] = (f32x4){0.f, 0.f, 0.f, 0.f};
        }
    }

    // ---- tile cb0 ----
    stage_write(lBt, wr, cq, ko);
    __syncthreads();
    compute_cb(lBt, feat, rowsum, wv, lane, quad, l15);
    do_targets(feat, w, margv, expdot, cb0 * CPB, tgt, wv, lane);

    // ---- tile cb1 ----
    if (has2) {
        __syncthreads();                   // all lBt reads of cb0 done
        stage_write(lBt, wr2, cq, ko);
        __syncthreads();
        compute_cb(lBt, feat, rowsum, wv, lane, quad, l15);
        do_targets(feat, w, margv, expdot, cb1 * CPB, tgt, wv, lane);
    }

    // ---- last-block finale ----
    __threadfence();                       // publish margv/expdot (+atomics)
    __syncthreads();
    if (tid == 0) sOld = atomicAdd(cnt, 1u);
    __syncthreads();
    if (sOld == GRID_MAIN - 1) {
        __threadfence();                   // acquire all blocks' writes
        float* red = (float*)lBt;          // reuse LDS
        const float m  = margv[tid];
        const float rs = rowsum[tid];
        const float dn = rs - OOB_PAD - expdot[tid] + expf(m);
        red[tid] = m - logf(dn);
        __syncthreads();
        #pragma unroll
        for (int st = 256; st > 0; st >>= 1) {
            if (tid < st) red[tid] += red[tid + st];
            __syncthreads();
        }
        if (tid == 0) out[0] = -red[0] / (float)B_ROWS;
    }
}

// ---------------------------------------------------------------------------
extern "C" void kernel_launch(void* const* d_in, const int* in_sizes, int n_in,
                              void* d_out, int out_size, void* d_ws, size_t ws_size,
                              hipStream_t stream)
{
    const float* feat   = (const float*)d_in[0];   // [512,128] fp32
    const float* w      = (const float*)d_in[1];   // [128,100000] fp32
    const int*   target = (const int*)d_in[2];     // [512]

    float*        rowsum = (float*)d_ws;                    // [512]
    unsigned int* cnt    = (unsigned int*)(rowsum + B_ROWS);// [1]
    float*        margv  = (float*)(cnt + 1);               // [512]
    float*        expdot = margv + B_ROWS;                  // [512]

    // zero rowsum + cnt (2052 B) each iteration; margv/expdot fully rewritten
    hipMemsetAsync(d_ws, 0, (B_ROWS + 1) * sizeof(float), stream);
    arc_main<<<dim3(GRID_MAIN), 512, 0, stream>>>(feat, w, target,
                                                  rowsum, margv, expdot,
                                                  cnt, (float*)d_out);
}

// Round 10
// 134.808 us; speedup vs baseline: 1.4645x; 1.4645x over previous
//
#include <hip/hip_runtime.h>

#define F_DIM   128
#define C_DIM   100000
#define B_ROWS  512
#define ANGLE   0.5f
#define CPB     128            // classes per tile
#define NCB     782            // ceil(100000/128); last tile has 96 OOB pad classes
#define OOB_PAD 96.0f          // pad classes contribute exp2(0)=1 each to row sums
#define LOG2E   1.4426950408889634f
#define GRID_MAIN 512          // 2 blocks/CU on 256 CUs; tiles grabbed dynamically

typedef __attribute__((ext_vector_type(4))) float        f32x4;
typedef __attribute__((ext_vector_type(8))) short        bf16x8;
typedef __attribute__((ext_vector_type(4))) unsigned int u32x4;

// packed fp32->bf16 (RNE), 2 elements per instruction
static __device__ __forceinline__ unsigned int pk2(float a, float b) {
    unsigned int r;
    asm("v_cvt_pk_bf16_f32 %0, %1, %2" : "=v"(r) : "v"(a), "v"(b));
    return r;
}

// ---------------------------------------------------------------------------
// arc_main: persistent grid 512 x 512 threads (2 blocks/CU). Tiles are
//   assigned DYNAMICALLY via a global atomic counter: exact load balance
//   (782 tiles over 512 blocks) and natural phase-stagger between the two
//   co-resident blocks on each CU (one stages while the other computes).
//   Staging / swizzle f(cls)=(cls&12)|((cls^(cls>>4))&3) / fB[2][4]
//   half-loop compute are byte-identical to the round-7-verified kernel.
//   The broadcast __syncthreads doubles as the lBt read->write barrier.
// ---------------------------------------------------------------------------
__global__ __launch_bounds__(512, 4)
void arc_main(const float* __restrict__ feat,
              const float* __restrict__ w,
              float* __restrict__ pp,        // [NCB][512]
              unsigned int* __restrict__ tilectr)  // [1], pre-zeroed
{
    __shared__ unsigned short lBt[128 * 128];   // [c][k] swizzled, 32 KB
    __shared__ int sCb;

    const int tid  = threadIdx.x;
    const int lane = tid & 63;
    const int wv   = tid >> 6;                // 0..7 -> 32-batch strip
    const int quad = lane >> 4;
    const int l15  = lane & 15;

    for (;;) {
        if (tid == 0) sCb = (int)atomicAdd(tilectr, 1u);
        __syncthreads();                      // broadcast + lBt reuse barrier
        const int cb = sCb;
        if (cb >= NCB) break;                 // block-uniform
        const int c0 = cb * CPB;

        // ---- stage w^T tile (x log2e): thread = (class-quad, k-octet) ----
        {
            const int cq = tid & 31;          // classes cq*4 .. cq*4+3
            const int ko = tid >> 5;          // k-octet 0..15
            const int gc = c0 + cq * 4;
            f32x4 wr[8];
            if (gc < C_DIM) {                 // whole quad valid (C%4==0)
                const float* wp = w + (size_t)ko * 8 * C_DIM + gc;
                #pragma unroll
                for (int i = 0; i < 8; ++i)
                    wr[i] = *(const f32x4*)(wp + (size_t)i * C_DIM);
            } else {
                #pragma unroll
                for (int i = 0; i < 8; ++i)
                    wr[i] = (f32x4){0.f, 0.f, 0.f, 0.f};
            }
            #pragma unroll
            for (int j = 0; j < 4; ++j) {
                const int cls = cq * 4 + j;
                union { u32x4 u; bf16x8 h; } c;
                c.u[0] = pk2(wr[0][j] * LOG2E, wr[1][j] * LOG2E);
                c.u[1] = pk2(wr[2][j] * LOG2E, wr[3][j] * LOG2E);
                c.u[2] = pk2(wr[4][j] * LOG2E, wr[5][j] * LOG2E);
                c.u[3] = pk2(wr[6][j] * LOG2E, wr[7][j] * LOG2E);
                const int f = (cls & 12) | ((cls ^ (cls >> 4)) & 3);
                *(bf16x8*)&lBt[cls * 128 + ((ko ^ f) << 3)] = c.h;
            }
        }
        __syncthreads();

        // ---- both 256-row halves reuse the staged tile ----
        #pragma unroll 1
        for (int half = 0; half < 2; ++half) {
            const int r0 = half << 8;

            // feat fragments: fB[s][ks] = f[b][k0..k0+7], b = r0+wv*32+s*16+l15
            bf16x8 fB[2][4];
            #pragma unroll
            for (int s = 0; s < 2; ++s) {
                const int b = r0 + wv * 32 + s * 16 + l15;
                #pragma unroll
                for (int ks = 0; ks < 4; ++ks) {
                    const int k0 = ks * 32 + quad * 8;
                    const f32x4 u0 = *(const f32x4*)(feat + b * F_DIM + k0);
                    const f32x4 u1 = *(const f32x4*)(feat + b * F_DIM + k0 + 4);
                    union { u32x4 u; bf16x8 h; } c;
                    c.u[0] = pk2(u0[0], u0[1]); c.u[1] = pk2(u0[2], u0[3]);
                    c.u[2] = pk2(u1[0], u1[1]); c.u[3] = pk2(u1[2], u1[3]);
                    fB[s][ks] = c.h;
                }
            }

            float eA0 = 0.f, eA1 = 0.f, eA2 = 0.f, eA3 = 0.f;   // s=0 col
            float eB0 = 0.f, eB1 = 0.f, eB2 = 0.f, eB3 = 0.f;   // s=1 col
            #pragma unroll
            for (int m = 0; m < 8; ++m) {
                f32x4 a0 = {0.f, 0.f, 0.f, 0.f};
                f32x4 a1 = {0.f, 0.f, 0.f, 0.f};
                const int rb = (m * 16 + l15) * 128;
                const int fr = (l15 & 12) | ((l15 ^ m) & 3);   // f(row)
                #pragma unroll
                for (int ks = 0; ks < 4; ++ks) {
                    const int pc = (ks * 4 + quad) ^ fr;
                    const bf16x8 af = *(const bf16x8*)&lBt[rb + (pc << 3)];
                    a0 = __builtin_amdgcn_mfma_f32_16x16x32_bf16(af, fB[0][ks], a0, 0, 0, 0);
                    a1 = __builtin_amdgcn_mfma_f32_16x16x32_bf16(af, fB[1][ks], a1, 0, 0, 0);
                }
                eA0 += __builtin_amdgcn_exp2f(a0[0]); eA1 += __builtin_amdgcn_exp2f(a0[1]);
                eA2 += __builtin_amdgcn_exp2f(a0[2]); eA3 += __builtin_amdgcn_exp2f(a0[3]);
                eB0 += __builtin_amdgcn_exp2f(a1[0]); eB1 += __builtin_amdgcn_exp2f(a1[1]);
                eB2 += __builtin_amdgcn_exp2f(a1[2]); eB3 += __builtin_amdgcn_exp2f(a1[3]);
            }

            float esum0 = (eA0 + eA1) + (eA2 + eA3);
            float esum1 = (eB0 + eB1) + (eB2 + eB3);
            // reduce across quads (same batch col holds different class rows)
            esum0 += __shfl_xor(esum0, 16); esum0 += __shfl_xor(esum0, 32);
            esum1 += __shfl_xor(esum1, 16); esum1 += __shfl_xor(esum1, 32);
            if (lane < 16) {
                const int r = r0 + wv * 32 + lane;
                pp[(size_t)cb * 512 + r]      = esum0;   // coalesced
                pp[(size_t)cb * 512 + r + 16] = esum1;
            }
        }
    }
}

// ---------------------------------------------------------------------------
// arc_row: exact fp32 target-column terms + pp row-sum. One wave per row.
// ---------------------------------------------------------------------------
__global__ void arc_row(const float* __restrict__ feat,
                        const float* __restrict__ w,
                        const int*   __restrict__ target,
                        const float* __restrict__ pp,
                        float* __restrict__ term)
{
    const int b    = blockIdx.x;
    const int lane = threadIdx.x;             // 64
    const int t    = target[b];

    float dot = 0.f, wsq = 0.f, fsq = 0.f, rs = 0.f;
    #pragma unroll
    for (int h = 0; h < 2; ++h) {
        const int f   = lane + h * 64;
        const float fv = feat[b * F_DIM + f];
        const float wc = w[(size_t)f * C_DIM + t];
        dot += fv * wc;
        wsq += wc * wc;
        fsq += fv * fv;
    }
    #pragma unroll
    for (int j = 0; j < 13; ++j) {            // 13*64 >= 782
        const int c = lane + j * 64;
        if (c < NCB) rs += pp[(size_t)c * 512 + b];
    }

    #pragma unroll
    for (int off = 32; off > 0; off >>= 1) {
        dot += __shfl_xor(dot, off);
        wsq += __shfl_xor(wsq, off);
        fsq += __shfl_xor(fsq, off);
        rs  += __shfl_xor(rs,  off);
    }
    if (lane == 0) {
        const float mod = sqrtf(fsq) * sqrtf(wsq);
        float ct = dot / (mod * 1.01f);
        ct = fminf(1.f, fmaxf(-1.f, ct));
        const float th   = acosf(ct) + ANGLE;
        const float marg = mod * cosf(th);
        const float down = rs - OOB_PAD - expf(dot) + expf(marg);
        term[b] = marg - logf(down);
    }
}

// ---------------------------------------------------------------------------
__global__ void arc_loss(const float* __restrict__ term,
                         float* __restrict__ out)
{
    __shared__ float red[B_ROWS];
    const int b = threadIdx.x;
    red[b] = term[b];
    __syncthreads();
    #pragma unroll
    for (int st = 256; st > 0; st >>= 1) {
        if (b < st) red[b] += red[b + st];
        __syncthreads();
    }
    if (b == 0) out[0] = -red[0] / (float)B_ROWS;
}

// ---------------------------------------------------------------------------
extern "C" void kernel_launch(void* const* d_in, const int* in_sizes, int n_in,
                              void* d_out, int out_size, void* d_ws, size_t ws_size,
                              hipStream_t stream)
{
    const float* feat   = (const float*)d_in[0];   // [512,128] fp32
    const float* w      = (const float*)d_in[1];   // [128,100000] fp32
    const int*   target = (const int*)d_in[2];     // [512]

    float*        pp      = (float*)d_ws;                  // [782][512]
    float*        term    = pp + (size_t)NCB * 512;        // [512]
    unsigned int* tilectr = (unsigned int*)(term + B_ROWS);// [1]

    hipMemsetAsync(tilectr, 0, sizeof(unsigned int), stream);
    arc_main<<<dim3(GRID_MAIN), 512, 0, stream>>>(feat, w, pp, tilectr);
    arc_row<<<B_ROWS, 64, 0, stream>>>(feat, w, target, pp, term);
    arc_loss<<<1, B_ROWS, 0, stream>>>(term, (float*)d_out);
}